// Round 2
// baseline (455.090 us; speedup 1.0000x reference)
//
#include <hip/hip_runtime.h>

// MultiCellLSTM: B=4096 chains, H=64, T=512, 3 cell types by t%4 (0,2,1,2).
// R5: TWO independent 16-row groups per block (512 thr, 8 waves, 128 blocks)
//     -> 2 waves/SIMD so one wave's latency stalls are filled by the other
//     (was 1 wave/SIMD, VALUBusy 52%, the step was latency-bound).
//  - x LDS staging DROPPED: x read straight from global per 4-step group
//    (group-ahead prefetch hides L1/L2 latency; per-block x1 slice = 32KB,
//    L1-resident), converted f32->bf16 in-register. LDS 33.8KB -> 9.2KB.
//  - __launch_bounds__(512,2): 2 waves/EU, VGPR cap 256 (need ~205).
// Carried from R4: operand-swapped MFMA (D = W.hx^T; h write-back =
// 2x v_cvt_pk_bf16_f32 + one ds_write_b64); bias as MFMA C-input; activation
// scale folded into weights (act = rcp(1+exp2(y))); x-MFMA issued first per
// gate to overlap hx ds_read_b128 latency; ONE barrier/step.
// Stale x2/x3 at off-phase steps are masked by zero weight columns.

typedef __attribute__((ext_vector_type(8))) short short8v;
typedef __attribute__((ext_vector_type(4))) float float4v;
typedef __attribute__((ext_vector_type(2))) float float2v;
typedef __attribute__((ext_vector_type(4))) unsigned short ushort4v;
typedef __attribute__((ext_vector_type(2))) unsigned int uint2v;

template <int N> struct IC { static constexpr int value = N; };

#define AST 72   // shorts per A row: 64 hx + 8 pad; 16B-aligned frags

#if __has_builtin(__builtin_amdgcn_exp2f)
#define EXP2F(x) __builtin_amdgcn_exp2f(x)
#else
#define EXP2F(x) exp2f(x)
#endif
#if __has_builtin(__builtin_amdgcn_rcpf)
#define RCPF(x) __builtin_amdgcn_rcpf(x)
#else
#define RCPF(x) (1.0f / (x))
#endif

#define NL2E -1.4426950408889634f   // -log2(e)
#define NL2E2 -2.8853900817779268f  // -2*log2(e)

__device__ __forceinline__ short f2bf(float f) {
  union { float f; unsigned u; } v; v.f = f;
  unsigned r = v.u + 0x7FFFu + ((v.u >> 16) & 1u);  // RNE
  return (short)(r >> 16);
}
__device__ __forceinline__ float bf2f(short h) {
  union { float f; unsigned u; } v;
  v.u = ((unsigned)(unsigned short)h) << 16;
  return v.f;
}
// pack two f32 -> two bf16 (RNE) in one instr
__device__ __forceinline__ unsigned cvt_pk_bf16(float lo, float hi) {
  unsigned r;
  asm("v_cvt_pk_bf16_f32 %0, %1, %2" : "=v"(r) : "v"(lo), "v"(hi));
  return r;
}
// act on pre-scaled y: sigmoid(x) = rcp(1+exp2(y)), y = x*NL2E
__device__ __forceinline__ float rcp1p(float y) {
  return RCPF(1.0f + EXP2F(y));
}
__device__ __forceinline__ float fsig(float x) { return rcp1p(x * NL2E); }
__device__ __forceinline__ float ftanh(float x) {
  return __builtin_fmaf(2.0f, rcp1p(x * NL2E2), -1.0f);
}

__global__ __launch_bounds__(512, 2) void mlstm_kernel(
    const float* __restrict__ x1, const float* __restrict__ x2,
    const float* __restrict__ x3,
    const float* __restrict__ Wi3, const float* __restrict__ Wh3,
    const float* __restrict__ bi3, const float* __restrict__ bh3,
    const float* __restrict__ Wi2, const float* __restrict__ Wh2,
    const float* __restrict__ bi2, const float* __restrict__ bh2,
    const float* __restrict__ Wi1, const float* __restrict__ Wh1,
    const float* __restrict__ bi1, const float* __restrict__ bh1,
    const float* __restrict__ Wout, const float* __restrict__ bout,
    float* __restrict__ out) {
  __shared__ __attribute__((aligned(16))) short Ab0[2][16 * AST];
  __shared__ __attribute__((aligned(16))) short Ab1[2][16 * AST];

  const int tid = threadIdx.x;   // 0..511
  const int sb = tid >> 8;       // sub-block (independent 16-row group) 0..1
  const int tid8 = tid & 255;
  const int w = tid8 >> 6;       // wave-within-group = h-col slice 0..3
  const int lane = tid & 63;
  const int q = lane >> 4;
  const int c = lane & 15;
  const int R0 = blockIdx.x * 32 + sb * 16;

  // ---- A buffers: hx(t=0) = 0 ----
  for (int idx = tid8; idx < 16 * AST; idx += 256) {
    Ab0[sb][idx] = 0;
    Ab1[sb][idx] = 0;
  }

  // ---- pack scaled weight fragments (per wave: tiles g=0..3) ----
  // whs[ty][g][kf]: lane(q,c) elem j = s_g * Wh[g*64+16w+c][kf*32+q*8+j]
  //   (swapped-mfma A operand: A[m=c][k=8q+j])
  // wix[ty][g]    : k = 8q+j -> q==0,j<3: s_g * Wi[n][j], else 0
  // bias4[ty][g]  : D-layout C-input: elem r = s_g*(bi+bh)[g*64+16w+4q+r]
  short8v whs[3][4][2];
  short8v wix[3][4];
  float4v bias4[3][4];
  {
    const float* WhA[3] = {Wh3, Wh2, Wh1};
    const float* WiA[3] = {Wi3, Wi2, Wi1};
    const float* biA[3] = {bi3, bi2, bi1};
    const float* bhA[3] = {bh3, bh2, bh1};
    const int wdt[3] = {3, 2, 1};
#pragma unroll
    for (int ty = 0; ty < 3; ++ty) {
#pragma unroll
      for (int g = 0; g < 4; ++g) {
        const float sg = (g == 2) ? NL2E2 : NL2E;
        const int n = g * 64 + 16 * w + c;
#pragma unroll
        for (int kf = 0; kf < 2; ++kf) {
          short8v v;
#pragma unroll
          for (int j = 0; j < 8; ++j)
            v[j] = f2bf(sg * WhA[ty][n * 64 + kf * 32 + q * 8 + j]);
          whs[ty][g][kf] = v;
        }
        short8v v2 = {0, 0, 0, 0, 0, 0, 0, 0};
        if (q == 0) {
#pragma unroll
          for (int j = 0; j < 3; ++j)
            if (j < wdt[ty]) v2[j] = f2bf(sg * WiA[ty][n * wdt[ty] + j]);
        }
        wix[ty][g] = v2;
        float4v bv;
#pragma unroll
        for (int r = 0; r < 4; ++r) {
          const int nd = g * 64 + 16 * w + 4 * q + r;  // D-row = gate col
          bv[r] = sg * (biA[ty][nd] + bhA[ty][nd]);
        }
        bias4[ty][g] = bv;
      }
    }
  }

  // addressing
  const int afo = c * AST + q * 8;          // hx B-frag base: n=c(row), k=q*8+j
  const int hwo = c * AST + 16 * w + 4 * q; // h write: row c, cols 16w+4q+r
  const short* Ar0 = &Ab0[sb][0];
  short* Aw0 = &Ab0[sb][0];
  const short* Ar1 = &Ab1[sb][0];
  short* Aw1 = &Ab1[sb][0];

  // global x row pointers for this lane's batch-row (broadcast across q, w)
  const float* xr1 = x1 + (size_t)(R0 + c) * 512;
  const float* xr2 = x2 + (size_t)(R0 + c) * 256;
  const float* xr3 = x3 + (size_t)(R0 + c) * 128;

  __syncthreads();

  float cx[4] = {0.f, 0.f, 0.f, 0.f};  // cell state: row c, hcol 16w+4q+r

  auto stepf = [&](auto tyc, auto sc, const short* rbuf, short* wbuf,
                   ushort4v xav, unsigned xbv, unsigned short xcv) {
    constexpr int TY = decltype(tyc)::value;
    constexpr int S = decltype(sc)::value;
    // x(t) B-frag values for batch-row c: only k=0..2 of wix nonzero;
    // stale x2/x3 (and q>0 lanes) are multiplied by zero weights.
    short x1s = (short)xav[S];
    short x2s = (short)((S < 2) ? (xbv & 0xFFFFu) : (xbv >> 16));
    short8v a2 = {x1s, x2s, (short)xcv, 0, 0, 0, 0, 0};
    short8v a0 = *(const short8v*)(rbuf + afo);
    short8v a1 = *(const short8v*)(rbuf + afo + 32);

    float4v acc[4];
#pragma unroll
    for (int g = 0; g < 4; ++g) {
      float4v z = bias4[TY][g];
      // x-MFMA first: register operands, overlaps a0/a1 LDS latency
      z = __builtin_amdgcn_mfma_f32_16x16x32_bf16(wix[TY][g], a2, z, 0, 0, 0);
      z = __builtin_amdgcn_mfma_f32_16x16x32_bf16(whs[TY][g][0], a0, z, 0, 0, 0);
      z = __builtin_amdgcn_mfma_f32_16x16x32_bf16(whs[TY][g][1], a1, z, 0, 0, 0);
      acc[g] = z;  // acc[g][r] = gate g, row c, hcol 16w+4q+r
    }

    float h[4];
#pragma unroll
    for (int r = 0; r < 4; ++r) {
      float si = rcp1p(acc[0][r]);                              // sigmoid(i)
      float sf = rcp1p(acc[1][r]);                              // sigmoid(f)
      float tg = __builtin_fmaf(2.0f, rcp1p(acc[2][r]), -1.0f); // tanh(g)
      float so = rcp1p(acc[3][r]);                              // sigmoid(o)
      float ncx = __builtin_fmaf(sf, cx[r], si * tg);
      cx[r] = ncx;
      h[r] = so * ftanh(ncx);
    }
    uint2v pk;
    pk[0] = cvt_pk_bf16(h[0], h[1]);
    pk[1] = cvt_pk_bf16(h[2], h[3]);
    *(uint2v*)(wbuf + hwo) = pk;  // one ds_write_b64, ~2-way banked
    __syncthreads();
  };

  // x loads for group t4=0
  float4v xf1 = *(const float4v*)(xr1);
  float2v xf2 = *(const float2v*)(xr2);
  float xf3 = xr3[0];
  // converted bf16 group values
  ushort4v xa;
  xa[0] = (unsigned short)f2bf(xf1[0]);
  xa[1] = (unsigned short)f2bf(xf1[1]);
  xa[2] = (unsigned short)f2bf(xf1[2]);
  xa[3] = (unsigned short)f2bf(xf1[3]);
  unsigned xb = ((unsigned)(unsigned short)f2bf(xf2[1]) << 16) |
                (unsigned)(unsigned short)f2bf(xf2[0]);
  unsigned short xc = (unsigned short)f2bf(xf3);

  // t%4 -> type: 0->0, 1->2, 2->1, 3->2
  for (int t4 = 0; t4 < 512; t4 += 4) {
    stepf(IC<0>{}, IC<0>{}, Ar0, Aw1, xa, xb, xc);
    // prefetch next group's x from global (clamped on last iter; unused)
    int tp = (t4 + 4 > 508) ? 508 : (t4 + 4);
    xf1 = *(const float4v*)(xr1 + tp);
    xf2 = *(const float2v*)(xr2 + (tp >> 1));
    xf3 = xr3[tp >> 2];
    stepf(IC<2>{}, IC<1>{}, Ar1, Aw0, xa, xb, xc);
    stepf(IC<1>{}, IC<2>{}, Ar0, Aw1, xa, xb, xc);
    stepf(IC<2>{}, IC<3>{}, Ar1, Aw0, xa, xb, xc);
    // convert prefetched group (off critical path; loads ~3 steps old)
    xa[0] = (unsigned short)f2bf(xf1[0]);
    xa[1] = (unsigned short)f2bf(xf1[1]);
    xa[2] = (unsigned short)f2bf(xf1[2]);
    xa[3] = (unsigned short)f2bf(xf1[3]);
    xb = ((unsigned)(unsigned short)f2bf(xf2[1]) << 16) |
         (unsigned)(unsigned short)f2bf(xf2[0]);
    xc = (unsigned short)f2bf(xf3);
  }
  // final hx (after 512 steps) is in Ab0[sb]

  if (tid8 < 16) {
    float s = bout[0];
    const short* hr = &Ab0[sb][0] + tid8 * AST;
#pragma unroll
    for (int k = 0; k < 64; ++k)
      s = __builtin_fmaf(bf2f(hr[k]), Wout[k], s);
    out[R0 + tid8] = fsig(s);
  }
}

extern "C" void kernel_launch(void* const* d_in, const int* in_sizes, int n_in,
                              void* d_out, int out_size, void* d_ws,
                              size_t ws_size, hipStream_t stream) {
  const float* x1 = (const float*)d_in[0];
  const float* x2 = (const float*)d_in[1];
  const float* x3 = (const float*)d_in[2];
  const float* Wi3 = (const float*)d_in[3];
  const float* Wh3 = (const float*)d_in[4];
  const float* bi3 = (const float*)d_in[5];
  const float* bh3 = (const float*)d_in[6];
  const float* Wi2 = (const float*)d_in[7];
  const float* Wh2 = (const float*)d_in[8];
  const float* bi2 = (const float*)d_in[9];
  const float* bh2 = (const float*)d_in[10];
  const float* Wi1 = (const float*)d_in[11];
  const float* Wh1 = (const float*)d_in[12];
  const float* bi1 = (const float*)d_in[13];
  const float* bh1 = (const float*)d_in[14];
  const float* Wout = (const float*)d_in[15];
  const float* bout = (const float*)d_in[16];
  float* out = (float*)d_out;

  hipLaunchKernelGGL(mlstm_kernel, dim3(128), dim3(512), 0, stream,
                     x1, x2, x3, Wi3, Wh3, bi3, bh3, Wi2, Wh2, bi2, bh2,
                     Wi1, Wh1, bi1, bh1, Wout, bout, out);
}

// Round 3
// 346.974 us; speedup vs baseline: 1.3116x; 1.3116x over previous
//
#include <hip/hip_runtime.h>

// MultiCellLSTM: B=4096 chains, H=64, T=512, 3 cell types by t%4 (0,2,1,2).
// R6: revert to R4 shape (256 thr, 4 waves, 256 blocks, 1 group/block) after
// R5's spill disaster (VGPR cap 128 -> 38MB scratch; and 128 blocks idled
// half the CUs for zero aggregate-issue gain). Changes vs R4:
//  - cell update reformulated to cut trans ops 10->8 per cell:
//      sig(i)*tanh(g) = (1-e2) * rcp((1+e0)(1+e2))
//      sig(o)*tanh(c) = (1-e4) * rcp((1+e3)(1+e4))
//    (one rcp per sigmoid*tanh pair instead of two; e = exp2 of pre-scaled
//    gate). exp2 args derived from unbounded cx are clamped at 60 to keep
//    the exact tanh->-1 saturation limit instead of inf*0 = NaN.
//  - x read from GLOBAL per 4-step group (R5's good piece): group-ahead
//    prefetch into regs, so x is off the post-barrier lgkm critical path;
//    conversion via 4x v_cvt_pk_bf16_f32 + 4x v_perm_b32 builds the four
//    per-step a2 dwords (replaces 7 scalar f2bf + extracts).
// Carried from R4: operand-swapped MFMA (D = W.hx^T; h write = 2x cvt_pk +
// one ds_write_b64); bias as MFMA C-input; activation scale folded into
// weights; x-MFMA first per gate to overlap hx ds_read_b128; ONE barrier/step.
// Stale x2/x3 at off-phase steps are masked by zero weight columns.

typedef __attribute__((ext_vector_type(8))) short short8v;
typedef __attribute__((ext_vector_type(4))) float float4v;
typedef __attribute__((ext_vector_type(2))) float float2v;
typedef __attribute__((ext_vector_type(4))) unsigned int uint4v;
typedef __attribute__((ext_vector_type(2))) unsigned int uint2v;

template <int N> struct IC { static constexpr int value = N; };

#define AST 72   // shorts per A row: 64 hx + 8 pad; 16B-aligned frags

#if __has_builtin(__builtin_amdgcn_exp2f)
#define EXP2F(x) __builtin_amdgcn_exp2f(x)
#else
#define EXP2F(x) exp2f(x)
#endif
#if __has_builtin(__builtin_amdgcn_rcpf)
#define RCPF(x) __builtin_amdgcn_rcpf(x)
#else
#define RCPF(x) (1.0f / (x))
#endif

#define NL2E -1.4426950408889634f   // -log2(e)
#define NL2E2 -2.8853900817779268f  // -2*log2(e)

__device__ __forceinline__ short f2bf(float f) {
  union { float f; unsigned u; } v; v.f = f;
  unsigned r = v.u + 0x7FFFu + ((v.u >> 16) & 1u);  // RNE
  return (short)(r >> 16);
}
__device__ __forceinline__ float bf2f(short h) {
  union { float f; unsigned u; } v;
  v.u = ((unsigned)(unsigned short)h) << 16;
  return v.f;
}
// pack two f32 -> two bf16 (RNE) in one instr
__device__ __forceinline__ unsigned cvt_pk_bf16(float lo, float hi) {
  unsigned r;
  asm("v_cvt_pk_bf16_f32 %0, %1, %2" : "=v"(r) : "v"(lo), "v"(hi));
  return r;
}
__device__ __forceinline__ unsigned permb(unsigned hi, unsigned lo, unsigned sel) {
#if __has_builtin(__builtin_amdgcn_perm)
  return __builtin_amdgcn_perm(hi, lo, sel);
#else
  union { unsigned u[2]; unsigned char b[8]; } s;
  s.u[0] = lo; s.u[1] = hi;
  unsigned r = 0;
  for (int i = 0; i < 4; ++i) r |= (unsigned)s.b[(sel >> (8 * i)) & 7] << (8 * i);
  return r;
#endif
}
// act on pre-scaled y: sigmoid(x) = rcp(1+exp2(y)), y = x*NL2E
__device__ __forceinline__ float rcp1p(float y) {
  return RCPF(1.0f + EXP2F(y));
}
__device__ __forceinline__ float fsig(float x) { return rcp1p(x * NL2E); }

__global__ __launch_bounds__(256, 1) void mlstm_kernel(
    const float* __restrict__ x1, const float* __restrict__ x2,
    const float* __restrict__ x3,
    const float* __restrict__ Wi3, const float* __restrict__ Wh3,
    const float* __restrict__ bi3, const float* __restrict__ bh3,
    const float* __restrict__ Wi2, const float* __restrict__ Wh2,
    const float* __restrict__ bi2, const float* __restrict__ bh2,
    const float* __restrict__ Wi1, const float* __restrict__ Wh1,
    const float* __restrict__ bi1, const float* __restrict__ bh1,
    const float* __restrict__ Wout, const float* __restrict__ bout,
    float* __restrict__ out) {
  __shared__ __attribute__((aligned(16))) short Ab0[16 * AST];
  __shared__ __attribute__((aligned(16))) short Ab1[16 * AST];

  const int tid = threadIdx.x;  // 0..255
  const int w = tid >> 6;       // wave = h-col slice 0..3
  const int lane = tid & 63;
  const int q = lane >> 4;
  const int c = lane & 15;
  const int R0 = blockIdx.x << 4;

  // ---- A buffers: hx(t=0) = 0 ----
  for (int idx = tid; idx < 16 * AST; idx += 256) {
    Ab0[idx] = 0;
    Ab1[idx] = 0;
  }

  // global x row pointers for this lane's batch-row (broadcast across q, w)
  const float* xr1 = x1 + (size_t)(R0 + c) * 512;
  const float* xr2 = x2 + (size_t)(R0 + c) * 256;
  const float* xr3 = x3 + (size_t)(R0 + c) * 128;

  // x loads for group t4=0 (issued early, before weight packing)
  float4v xf1 = *(const float4v*)(xr1);
  float2v xf2 = *(const float2v*)(xr2);
  float xf3 = xr3[0];

  // ---- pack scaled weight fragments (per wave: tiles g=0..3) ----
  // whs[ty][g][kf]: lane(q,c) elem j = s_g * Wh[g*64+16w+c][kf*32+q*8+j]
  //   (swapped-mfma A operand: A[m=c][k=8q+j])
  // wix[ty][g]    : k = 8q+j -> q==0,j<3: s_g * Wi[n][j], else 0
  // bias4[ty][g]  : D-layout C-input: elem r = s_g*(bi+bh)[g*64+16w+4q+r]
  short8v whs[3][4][2];
  short8v wix[3][4];
  float4v bias4[3][4];
  {
    const float* WhA[3] = {Wh3, Wh2, Wh1};
    const float* WiA[3] = {Wi3, Wi2, Wi1};
    const float* biA[3] = {bi3, bi2, bi1};
    const float* bhA[3] = {bh3, bh2, bh1};
    const int wdt[3] = {3, 2, 1};
#pragma unroll
    for (int ty = 0; ty < 3; ++ty) {
#pragma unroll
      for (int g = 0; g < 4; ++g) {
        const float sg = (g == 2) ? NL2E2 : NL2E;
        const int n = g * 64 + 16 * w + c;
#pragma unroll
        for (int kf = 0; kf < 2; ++kf) {
          short8v v;
#pragma unroll
          for (int j = 0; j < 8; ++j)
            v[j] = f2bf(sg * WhA[ty][n * 64 + kf * 32 + q * 8 + j]);
          whs[ty][g][kf] = v;
        }
        short8v v2 = {0, 0, 0, 0, 0, 0, 0, 0};
        if (q == 0) {
#pragma unroll
          for (int j = 0; j < 3; ++j)
            if (j < wdt[ty]) v2[j] = f2bf(sg * WiA[ty][n * wdt[ty] + j]);
        }
        wix[ty][g] = v2;
        float4v bv;
#pragma unroll
        for (int r = 0; r < 4; ++r) {
          const int nd = g * 64 + 16 * w + 4 * q + r;  // D-row = gate col
          bv[r] = sg * (biA[ty][nd] + bhA[ty][nd]);
        }
        bias4[ty][g] = bv;
      }
    }
  }

  // addressing
  const int afo = c * AST + q * 8;          // hx B-frag base: n=c(row), k=q*8+j
  const int hwo = c * AST + 16 * w + 4 * q; // h write: row c, cols 16w+4q+r

  __syncthreads();

  float cx[4] = {0.f, 0.f, 0.f, 0.f};  // cell state: row c, hcol 16w+4q+r

  // per-group a2 dwords: dS = x1[t4+S] | (x2[(t4+S)/2] << 16); xcw = x3[t4/4]
  unsigned d0, d1, d2, d3, xcw;
  auto cvtgrp = [&]() {
    unsigned pA = cvt_pk_bf16(xf1[0], xf1[1]);
    unsigned pB = cvt_pk_bf16(xf1[2], xf1[3]);
    unsigned p2 = cvt_pk_bf16(xf2[0], xf2[1]);
    xcw = cvt_pk_bf16(xf3, 0.0f);  // high short = bf16(0) = 0
    d0 = permb(p2, pA, 0x05040100);  // x1[0] | x2lo<<16
    d1 = permb(p2, pA, 0x05040302);  // x1[1] | x2lo<<16
    d2 = permb(p2, pB, 0x07060100);  // x1[2] | x2hi<<16
    d3 = permb(p2, pB, 0x07060302);  // x1[3] | x2hi<<16
  };
  cvtgrp();

  auto stepf = [&](auto tyc, unsigned dS, unsigned dx3, const short* rbuf,
                   short* wbuf) {
    constexpr int TY = decltype(tyc)::value;
    // x(t) B-frag: only k=0..2 of wix nonzero; stale x2/x3 (and q>0 lanes)
    // are multiplied by zero weights.
    uint4v au = {dS, dx3, 0u, 0u};
    short8v a2 = __builtin_bit_cast(short8v, au);
    short8v a0 = *(const short8v*)(rbuf + afo);
    short8v a1 = *(const short8v*)(rbuf + afo + 32);

    float4v acc[4];
#pragma unroll
    for (int g = 0; g < 4; ++g) {
      float4v z = bias4[TY][g];
      // x-MFMA first: register operands, overlaps a0/a1 LDS latency
      z = __builtin_amdgcn_mfma_f32_16x16x32_bf16(wix[TY][g], a2, z, 0, 0, 0);
      z = __builtin_amdgcn_mfma_f32_16x16x32_bf16(whs[TY][g][0], a0, z, 0, 0, 0);
      z = __builtin_amdgcn_mfma_f32_16x16x32_bf16(whs[TY][g][1], a1, z, 0, 0, 0);
      acc[g] = z;  // acc[g][r] = gate g, row c, hcol 16w+4q+r
    }

    float h[4];
#pragma unroll
    for (int r = 0; r < 4; ++r) {
      // e = exp2 of pre-scaled gates: e0=e^-i, e1=e^-f, e2=e^-2g, e3=e^-o
      float e0 = EXP2F(acc[0][r]);
      float e1 = EXP2F(acc[1][r]);
      float e2 = EXP2F(__builtin_fminf(acc[2][r], 60.0f));
      float e3 = EXP2F(acc[3][r]);
      // sig(i)*tanh(g) = (1-e2) / ((1+e0)(1+e2))
      float sitg = (1.0f - e2) * RCPF((1.0f + e0) * (1.0f + e2));
      float ncx = __builtin_fmaf(RCPF(1.0f + e1), cx[r], sitg);
      cx[r] = ncx;
      // sig(o)*tanh(ncx) = (1-e4) / ((1+e3)(1+e4)), e4 = e^-2ncx (clamped:
      // cx is unbounded over 512 steps; clamp keeps exact tanh->-1 limit)
      float e4 = EXP2F(__builtin_fminf(ncx * NL2E2, 60.0f));
      h[r] = (1.0f - e4) * RCPF((1.0f + e3) * (1.0f + e4));
    }
    uint2v pk;
    pk[0] = cvt_pk_bf16(h[0], h[1]);
    pk[1] = cvt_pk_bf16(h[2], h[3]);
    *(uint2v*)(wbuf + hwo) = pk;  // one ds_write_b64, ~2-way banked
    __syncthreads();
  };

  // t%4 -> type: 0->0, 1->2, 2->1, 3->2
  for (int t4 = 0; t4 < 512; t4 += 4) {
    stepf(IC<0>{}, d0, xcw, Ab0, Ab1);
    // prefetch next group's x from global (clamped on last iter; unused)
    int tp = (t4 + 4 > 508) ? 508 : (t4 + 4);
    xf1 = *(const float4v*)(xr1 + tp);
    xf2 = *(const float2v*)(xr2 + (tp >> 1));
    xf3 = xr3[tp >> 2];
    stepf(IC<2>{}, d1, xcw, Ab1, Ab0);
    stepf(IC<1>{}, d2, xcw, Ab0, Ab1);
    stepf(IC<2>{}, d3, xcw, Ab1, Ab0);
    // convert prefetched group (off critical path; loads ~3 steps old)
    cvtgrp();
  }
  // final hx (after 512 steps) is in Ab0

  if (tid < 16) {
    float s = bout[0];
    const short* hr = Ab0 + tid * AST;
#pragma unroll
    for (int k = 0; k < 64; ++k)
      s = __builtin_fmaf(bf2f(hr[k]), Wout[k], s);
    out[R0 + tid] = fsig(s);
  }
}

extern "C" void kernel_launch(void* const* d_in, const int* in_sizes, int n_in,
                              void* d_out, int out_size, void* d_ws,
                              size_t ws_size, hipStream_t stream) {
  const float* x1 = (const float*)d_in[0];
  const float* x2 = (const float*)d_in[1];
  const float* x3 = (const float*)d_in[2];
  const float* Wi3 = (const float*)d_in[3];
  const float* Wh3 = (const float*)d_in[4];
  const float* bi3 = (const float*)d_in[5];
  const float* bh3 = (const float*)d_in[6];
  const float* Wi2 = (const float*)d_in[7];
  const float* Wh2 = (const float*)d_in[8];
  const float* bi2 = (const float*)d_in[9];
  const float* bh2 = (const float*)d_in[10];
  const float* Wi1 = (const float*)d_in[11];
  const float* Wh1 = (const float*)d_in[12];
  const float* bi1 = (const float*)d_in[13];
  const float* bh1 = (const float*)d_in[14];
  const float* Wout = (const float*)d_in[15];
  const float* bout = (const float*)d_in[16];
  float* out = (float*)d_out;

  hipLaunchKernelGGL(mlstm_kernel, dim3(256), dim3(256), 0, stream,
                     x1, x2, x3, Wi3, Wh3, bi3, bh3, Wi2, Wh2, bi2, bh2,
                     Wi1, Wh1, bi1, bh1, Wout, bout, out);
}

// Round 4
// 299.363 us; speedup vs baseline: 1.5202x; 1.1590x over previous
//
#include <hip/hip_runtime.h>

// MultiCellLSTM: B=4096 chains, H=64, T=512, 3 cell types by t%4 (0,2,1,2).
// R7: consolidation after R6's regression. R6's global-x prefetch was
// re-drained by __syncthreads (vmcnt(0) before s_barrier) -> 300-900cy of
// L2/HBM latency exposed once per 4-step group. Fix: x back in LDS, and
// PRE-PACKED: xAf[c][t] = bf16(x1[t]) | bf16(x2[t>>1])<<16, xBf[c][t4] =
// bf16(x3). Per group: one ds_read_b128 + one ds_read_b32 (prefetched a
// group ahead, lgkm-only, hidden by one step); per-step a2 = register
// placement, zero VALU.
// Kept from R6 and extended: merged-rcp activation, now 7 trans/cell
// (5 exp2 + 2 rcp; R4 had 10):
//   a=1+e^-i, b=1+e^-f, g2=1+e^-2g  (e via exp2 of pre-scaled gates)
//   ncx = (cx*a*g2 + (1-e2)*b) * rcp(a*b*g2)
//   h   = (1-e4) * rcp((1+e3)(1+e4)),  e4 = e^-2ncx (clamped at 2^60)
// Carried from R4: 256 thr / 4 waves / 256 blocks; operand-swapped MFMA
// (D = W.hx^T; h write = 2x cvt_pk + one ds_write_b64); bias as MFMA
// C-input; activation scale folded into weights; x-MFMA first per gate to
// overlap hx ds_read_b128; ONE barrier/step.
// Stale x2/x3 at off-phase steps are masked by zero weight columns.

typedef __attribute__((ext_vector_type(8))) short short8v;
typedef __attribute__((ext_vector_type(4))) float float4v;
typedef __attribute__((ext_vector_type(2))) float float2v;
typedef __attribute__((ext_vector_type(4))) unsigned int uint4v;
typedef __attribute__((ext_vector_type(2))) unsigned int uint2v;

template <int N> struct IC { static constexpr int value = N; };

#define AST 72    // shorts per A row: 64 hx + 8 pad; 16B-aligned frags
#define XSA 516   // dwords per xA row: 512 + 4 pad -> banks 4c mod 32, 2-way (free)
#define XSB 129   // dwords per xB row: 128 + 1 pad -> bank c+t mod 32, conflict-free

#if __has_builtin(__builtin_amdgcn_exp2f)
#define EXP2F(x) __builtin_amdgcn_exp2f(x)
#else
#define EXP2F(x) exp2f(x)
#endif
#if __has_builtin(__builtin_amdgcn_rcpf)
#define RCPF(x) __builtin_amdgcn_rcpf(x)
#else
#define RCPF(x) (1.0f / (x))
#endif

#define NL2E -1.4426950408889634f   // -log2(e)
#define NL2E2 -2.8853900817779268f  // -2*log2(e)

__device__ __forceinline__ short f2bf(float f) {
  union { float f; unsigned u; } v; v.f = f;
  unsigned r = v.u + 0x7FFFu + ((v.u >> 16) & 1u);  // RNE
  return (short)(r >> 16);
}
__device__ __forceinline__ float bf2f(short h) {
  union { float f; unsigned u; } v;
  v.u = ((unsigned)(unsigned short)h) << 16;
  return v.f;
}
// pack two f32 -> two bf16 (RNE) in one instr: lo | hi<<16
__device__ __forceinline__ unsigned cvt_pk_bf16(float lo, float hi) {
  unsigned r;
  asm("v_cvt_pk_bf16_f32 %0, %1, %2" : "=v"(r) : "v"(lo), "v"(hi));
  return r;
}
// act on pre-scaled y: sigmoid(x) = rcp(1+exp2(y)), y = x*NL2E
__device__ __forceinline__ float rcp1p(float y) {
  return RCPF(1.0f + EXP2F(y));
}
__device__ __forceinline__ float fsig(float x) { return rcp1p(x * NL2E); }

__global__ __launch_bounds__(256, 1) void mlstm_kernel(
    const float* __restrict__ x1, const float* __restrict__ x2,
    const float* __restrict__ x3,
    const float* __restrict__ Wi3, const float* __restrict__ Wh3,
    const float* __restrict__ bi3, const float* __restrict__ bh3,
    const float* __restrict__ Wi2, const float* __restrict__ Wh2,
    const float* __restrict__ bi2, const float* __restrict__ bh2,
    const float* __restrict__ Wi1, const float* __restrict__ Wh1,
    const float* __restrict__ bi1, const float* __restrict__ bh1,
    const float* __restrict__ Wout, const float* __restrict__ bout,
    float* __restrict__ out) {
  __shared__ __attribute__((aligned(16))) short Ab0[16 * AST];
  __shared__ __attribute__((aligned(16))) short Ab1[16 * AST];
  __shared__ __attribute__((aligned(16))) unsigned xAf[16 * XSA];
  __shared__ __attribute__((aligned(16))) unsigned xBf[16 * XSB];

  const int tid = threadIdx.x;  // 0..255
  const int w = tid >> 6;       // wave = h-col slice 0..3
  const int lane = tid & 63;
  const int q = lane >> 4;
  const int c = lane & 15;
  const int R0 = blockIdx.x << 4;

  // ---- preload x into LDS, pre-packed as a2 dwords ----
  // xAf[m][t] = bf16(x1[m][t]) | bf16(x2[m][t>>1])<<16
  for (int idx = tid; idx < 16 * 256; idx += 256) {
    int m = idx >> 8, tp = idx & 255;
    float2v v1 = *(const float2v*)(x1 + (size_t)(R0 + m) * 512 + 2 * tp);
    float v2 = x2[(size_t)(R0 + m) * 256 + tp];
    xAf[m * XSA + 2 * tp] = cvt_pk_bf16(v1[0], v2);
    xAf[m * XSA + 2 * tp + 1] = cvt_pk_bf16(v1[1], v2);
  }
  // xBf[m][tt] = bf16(x3[m][tt]) (high short = 0)
  for (int idx = tid; idx < 16 * 128; idx += 256) {
    int m = idx >> 7, tt = idx & 127;
    xBf[m * XSB + tt] = cvt_pk_bf16(x3[(size_t)(R0 + m) * 128 + tt], 0.0f);
  }
  // ---- A buffers: hx(t=0) = 0 ----
  for (int idx = tid; idx < 16 * AST; idx += 256) {
    Ab0[idx] = 0;
    Ab1[idx] = 0;
  }

  // ---- pack scaled weight fragments (per wave: tiles g=0..3) ----
  // whs[ty][g][kf]: lane(q,c) elem j = s_g * Wh[g*64+16w+c][kf*32+q*8+j]
  //   (swapped-mfma A operand: A[m=c][k=8q+j])
  // wix[ty][g]    : k = 8q+j -> q==0,j<3: s_g * Wi[n][j], else 0
  // bias4[ty][g]  : D-layout C-input: elem r = s_g*(bi+bh)[g*64+16w+4q+r]
  short8v whs[3][4][2];
  short8v wix[3][4];
  float4v bias4[3][4];
  {
    const float* WhA[3] = {Wh3, Wh2, Wh1};
    const float* WiA[3] = {Wi3, Wi2, Wi1};
    const float* biA[3] = {bi3, bi2, bi1};
    const float* bhA[3] = {bh3, bh2, bh1};
    const int wdt[3] = {3, 2, 1};
#pragma unroll
    for (int ty = 0; ty < 3; ++ty) {
#pragma unroll
      for (int g = 0; g < 4; ++g) {
        const float sg = (g == 2) ? NL2E2 : NL2E;
        const int n = g * 64 + 16 * w + c;
#pragma unroll
        for (int kf = 0; kf < 2; ++kf) {
          short8v v;
#pragma unroll
          for (int j = 0; j < 8; ++j)
            v[j] = f2bf(sg * WhA[ty][n * 64 + kf * 32 + q * 8 + j]);
          whs[ty][g][kf] = v;
        }
        short8v v2 = {0, 0, 0, 0, 0, 0, 0, 0};
        if (q == 0) {
#pragma unroll
          for (int j = 0; j < 3; ++j)
            if (j < wdt[ty]) v2[j] = f2bf(sg * WiA[ty][n * wdt[ty] + j]);
        }
        wix[ty][g] = v2;
        float4v bv;
#pragma unroll
        for (int r = 0; r < 4; ++r) {
          const int nd = g * 64 + 16 * w + 4 * q + r;  // D-row = gate col
          bv[r] = sg * (biA[ty][nd] + bhA[ty][nd]);
        }
        bias4[ty][g] = bv;
      }
    }
  }

  // addressing
  const int afo = c * AST + q * 8;          // hx B-frag base: n=c(row), k=q*8+j
  const int hwo = c * AST + 16 * w + 4 * q; // h write: row c, cols 16w+4q+r
  const int xao = c * XSA;                  // xA row base (broadcast across q,w)
  const int xbo = c * XSB;

  __syncthreads();

  float cx[4] = {0.f, 0.f, 0.f, 0.f};  // cell state: row c, hcol 16w+4q+r

  auto stepf = [&](auto tyc, unsigned dS, unsigned dx3, const short* rbuf,
                   short* wbuf) {
    constexpr int TY = decltype(tyc)::value;
    // x(t) B-frag: k0=x1, k1=x2, k2=x3, rest 0; stale x2/x3 (and q>0
    // lanes) are multiplied by zero weight columns.
    uint4v au = {dS, dx3, 0u, 0u};
    short8v a2 = __builtin_bit_cast(short8v, au);
    short8v a0 = *(const short8v*)(rbuf + afo);
    short8v a1 = *(const short8v*)(rbuf + afo + 32);

    float4v acc[4];
#pragma unroll
    for (int g = 0; g < 4; ++g) {
      float4v z = bias4[TY][g];
      // x-MFMA first: register operands, overlaps a0/a1 LDS latency
      z = __builtin_amdgcn_mfma_f32_16x16x32_bf16(wix[TY][g], a2, z, 0, 0, 0);
      z = __builtin_amdgcn_mfma_f32_16x16x32_bf16(whs[TY][g][0], a0, z, 0, 0, 0);
      z = __builtin_amdgcn_mfma_f32_16x16x32_bf16(whs[TY][g][1], a1, z, 0, 0, 0);
      acc[g] = z;  // acc[g][r] = gate g, row c, hcol 16w+4q+r
    }

    float h[4];
#pragma unroll
    for (int r = 0; r < 4; ++r) {
      // e = exp2 of pre-scaled gates: e0=e^-i, e1=e^-f, e2=e^-2g, e3=e^-o
      float e0 = EXP2F(acc[0][r]);
      float e1 = EXP2F(acc[1][r]);
      float e2 = EXP2F(__builtin_fminf(acc[2][r], 60.0f));
      float e3 = EXP2F(acc[3][r]);
      float a = 1.0f + e0, b = 1.0f + e1, g2 = 1.0f + e2;
      float ag = a * g2;
      float Rr = RCPF(ag * b);  // one rcp for sig(f), sig(i)*tanh(g)
      float ncx = (__builtin_fmaf(cx[r], ag, (1.0f - e2) * b)) * Rr;
      cx[r] = ncx;
      // sig(o)*tanh(ncx) = (1-e4) / ((1+e3)(1+e4)); clamp keeps the exact
      // tanh->-1 saturation limit instead of inf*0 = NaN
      float e4 = EXP2F(__builtin_fminf(ncx * NL2E2, 60.0f));
      h[r] = (1.0f - e4) * RCPF((1.0f + e3) * (1.0f + e4));
    }
    uint2v pk;
    pk[0] = cvt_pk_bf16(h[0], h[1]);
    pk[1] = cvt_pk_bf16(h[2], h[3]);
    *(uint2v*)(wbuf + hwo) = pk;  // one ds_write_b64, ~2-way banked
    __syncthreads();
  };

  // x dwords for group t4=0
  uint4v xd = *(const uint4v*)(xAf + xao);
  unsigned xw = xBf[xbo];

  // t%4 -> type: 0->0, 1->2, 2->1, 3->2
  for (int t4 = 0; t4 < 512; t4 += 4) {
    stepf(IC<0>{}, xd[0], xw, Ab0, Ab1);
    // prefetch next group's x from LDS (clamped on last iter; unused).
    // lgkm-only; fully hidden by one step even with barrier drains.
    int tp = (t4 + 4 > 508) ? 508 : (t4 + 4);
    uint4v xdn = *(const uint4v*)(xAf + xao + tp);
    unsigned xwn = xBf[xbo + (tp >> 2)];
    stepf(IC<2>{}, xd[1], xw, Ab1, Ab0);
    stepf(IC<1>{}, xd[2], xw, Ab0, Ab1);
    stepf(IC<2>{}, xd[3], xw, Ab1, Ab0);
    xd = xdn;
    xw = xwn;
  }
  // final hx (after 512 steps) is in Ab0

  if (tid < 16) {
    float s = bout[0];
    const short* hr = Ab0 + tid * AST;
#pragma unroll
    for (int k = 0; k < 64; ++k)
      s = __builtin_fmaf(bf2f(hr[k]), Wout[k], s);
    out[R0 + tid] = fsig(s);
  }
}

extern "C" void kernel_launch(void* const* d_in, const int* in_sizes, int n_in,
                              void* d_out, int out_size, void* d_ws,
                              size_t ws_size, hipStream_t stream) {
  const float* x1 = (const float*)d_in[0];
  const float* x2 = (const float*)d_in[1];
  const float* x3 = (const float*)d_in[2];
  const float* Wi3 = (const float*)d_in[3];
  const float* Wh3 = (const float*)d_in[4];
  const float* bi3 = (const float*)d_in[5];
  const float* bh3 = (const float*)d_in[6];
  const float* Wi2 = (const float*)d_in[7];
  const float* Wh2 = (const float*)d_in[8];
  const float* bi2 = (const float*)d_in[9];
  const float* bh2 = (const float*)d_in[10];
  const float* Wi1 = (const float*)d_in[11];
  const float* Wh1 = (const float*)d_in[12];
  const float* bi1 = (const float*)d_in[13];
  const float* bh1 = (const float*)d_in[14];
  const float* Wout = (const float*)d_in[15];
  const float* bout = (const float*)d_in[16];
  float* out = (float*)d_out;

  hipLaunchKernelGGL(mlstm_kernel, dim3(256), dim3(256), 0, stream,
                     x1, x2, x3, Wi3, Wh3, bi3, bh3, Wi2, Wh2, bi2, bh2,
                     Wi1, Wh1, bi1, bh1, Wout, bout, out);
}